// Round 4
// baseline (121.538 us; speedup 1.0000x reference)
//
#include <hip/hip_runtime.h>

// VQ-VAE forward, two-stage argmin:
//   1) coarse fp16 MFMA GEMM (K=256) + fused top-2-per-nb candidate extraction
//   2) exact f32 refinement of ~1-2 candidates/point + gather + loss
// d_out: [0,8388608) quantized f32 | [8388608] loss | [8388609,+1024) usage
// d_out[0,16MiB) doubles as the f16 A-image (conv -> coarse), overwritten by refine.
// d_ws: [0,512K) W-f16 image | +4K wsq | +2M best2 (u32 key22|idx10) | +1K partial.

typedef _Float16 f16;
typedef __attribute__((ext_vector_type(8))) f16 f16x8;
typedef __attribute__((ext_vector_type(4))) float f32x4;
typedef unsigned int u32;

#define NQ 8388608

__device__ __forceinline__ u32 sortkey(float f) {
    u32 u = __float_as_uint(f);
    return (u & 0x80000000u) ? ~u : (u | 0x80000000u);
}
__device__ __forceinline__ float inv_sortkey(u32 u) {
    return (u & 0x80000000u) ? __uint_as_float(u & 0x7FFFFFFFu) : __uint_as_float(~u);
}

// ---- merged conversion kernel ----
// blocks 0..255: inputs -> A-f16 image [mb 0..255][t 0..7][cg 0..3][row 0..127][16B]
// blocks 256..383: weight -> W-f16 image [nb 0..7][t][cg][col][16B] + wsq + usage=0
extern "C" __global__ __launch_bounds__(256) void vq_conv(const float* __restrict__ inp,
                                                          const float* __restrict__ w,
                                                          char* __restrict__ Aimg,
                                                          char* __restrict__ Wimg,
                                                          float* __restrict__ wsq,
                                                          float* __restrict__ usage) {
    int blk = blockIdx.x, tid = threadIdx.x;
    if (blk < 256) {
        __shared__ float xt[64 * 128];
        int mb = blk;
        int b = mb >> 3, hw0 = (mb & 7) * 128;
        const float* base = inp + (size_t)b * 262144 + hw0;
        char* Ab = Aimg + (size_t)mb * 65536;
        for (int dcb = 0; dcb < 4; ++dcb) {
            __syncthreads();
            #pragma unroll
            for (int it = 0; it < 8; ++it) {
                int e = it * 256 + tid;
                int dd = e >> 5, h4 = e & 31;
                float4 v = *(const float4*)(base + (size_t)(dcb * 64 + dd) * 1024 + h4 * 4);
                *(float4*)(xt + dd * 128 + h4 * 4) = v;
            }
            __syncthreads();
            #pragma unroll
            for (int it2 = 0; it2 < 4; ++it2) {
                int task = it2 * 256 + tid;
                int g = task >> 7, row = task & 127;
                union { f16 h[8]; uint4 v; } pk;
                #pragma unroll
                for (int j = 0; j < 8; ++j) pk.h[j] = (f16)xt[(g * 8 + j) * 128 + row];
                int t_img = dcb * 2 + (g >> 2), cg = g & 3;
                *(uint4*)(Ab + (size_t)t_img * 8192 + cg * 2048 + row * 16) = pk.v;
            }
        }
    } else {
        int gid = (blk - 256) * 256 + tid;  // 32768 = 1024 n x 32 dc
        int n = gid >> 5, dc = gid & 31;
        const float* src = w + n * 256 + dc * 8;
        float4 v0 = *(const float4*)src;
        float4 v1 = *(const float4*)(src + 4);
        float xs[8] = {v0.x, v0.y, v0.z, v0.w, v1.x, v1.y, v1.z, v1.w};
        union { f16 h[8]; uint4 v; } pk;
        float sq = 0.0f;
        #pragma unroll
        for (int j = 0; j < 8; ++j) {
            pk.h[j] = (f16)xs[j];
            sq += xs[j] * xs[j];
        }
        int nb = n >> 7, col = n & 127;
        *(uint4*)(Wimg + (size_t)nb * 65536 + (dc >> 2) * 8192 + (dc & 3) * 2048 + col * 16) = pk.v;
        #pragma unroll
        for (int m = 1; m <= 16; m <<= 1) sq += __shfl_xor(sq, m, 64);
        if ((tid & 31) == 0) { wsq[n] = sq; usage[n] = 0.0f; }
    }
}

// ---- coarse fp16 GEMM 128x128xK256 + fused top-2-per-nb argmin ----
extern "C" __global__ __launch_bounds__(256) void vq_coarse(const char* __restrict__ Aimg,
                                                            const char* __restrict__ Wimg,
                                                            const float* __restrict__ wsq,
                                                            u32* __restrict__ best2) {
    __shared__ __align__(16) char smem[32768];  // 2 bufs x (A 8K + B 8K)
    __shared__ u32 red2[128][2][2];
    const int tid = threadIdx.x, lane = tid & 63, wv = tid >> 6;
    const int wm = wv >> 1, wn = wv & 1;
    const int rm = wm * 64, cn = wn * 64;
    const int cg = lane >> 4, rl = lane & 15;
    int bid = blockIdx.x;
    int lb = (bid & 7) * 256 + (bid >> 3);  // XCD-chunked swizzle (2048 % 8 == 0)
    const int mb = lb >> 3, nb = lb & 7;

    const char* Ag = Aimg + (size_t)mb * 65536;
    const char* Bg = Wimg + (size_t)nb * 65536;

    f32x4 acc[4][4];
    #pragma unroll
    for (int i = 0; i < 4; ++i)
        #pragma unroll
        for (int j = 0; j < 4; ++j) acc[i][j] = (f32x4){0.f, 0.f, 0.f, 0.f};

    auto stage = [&](int T) {
        const char* ga = Ag + (size_t)T * 8192;
        const char* gb = Bg + (size_t)T * 8192;
        char* la = smem + (T & 1) * 16384;
        char* lb2 = la + 8192;
        __builtin_amdgcn_global_load_lds(
            (const __attribute__((address_space(1))) u32*)(ga + tid * 16),
            (__attribute__((address_space(3))) u32*)(la + tid * 16), 16, 0, 0);
        __builtin_amdgcn_global_load_lds(
            (const __attribute__((address_space(1))) u32*)(ga + tid * 16 + 4096),
            (__attribute__((address_space(3))) u32*)(la + tid * 16 + 4096), 16, 0, 0);
        __builtin_amdgcn_global_load_lds(
            (const __attribute__((address_space(1))) u32*)(gb + tid * 16),
            (__attribute__((address_space(3))) u32*)(lb2 + tid * 16), 16, 0, 0);
        __builtin_amdgcn_global_load_lds(
            (const __attribute__((address_space(1))) u32*)(gb + tid * 16 + 4096),
            (__attribute__((address_space(3))) u32*)(lb2 + tid * 16 + 4096), 16, 0, 0);
    };

    stage(0);
    asm volatile("s_waitcnt vmcnt(0)" ::: "memory");
    __builtin_amdgcn_s_barrier();

    for (int T = 0; T < 8; ++T) {
        if (T < 7) stage(T + 1);
        const char* Ab = smem + (T & 1) * 16384 + cg * 2048;
        const char* Bb = Ab + 8192;
        f16x8 af[4], bf[4];
        #pragma unroll
        for (int f = 0; f < 4; ++f) {
            af[f] = *(const f16x8*)(Ab + (rm + f * 16 + rl) * 16);
            bf[f] = *(const f16x8*)(Bb + (cn + f * 16 + rl) * 16);
        }
        __builtin_amdgcn_sched_barrier(0);
        asm volatile("s_waitcnt lgkmcnt(0)" ::: "memory");
        __builtin_amdgcn_sched_barrier(0);
        __builtin_amdgcn_s_setprio(1);
        #pragma unroll
        for (int fi = 0; fi < 4; ++fi)
            #pragma unroll
            for (int fj = 0; fj < 4; ++fj)
                acc[fi][fj] = __builtin_amdgcn_mfma_f32_16x16x32_f16(af[fi], bf[fj],
                                                                    acc[fi][fj], 0, 0, 0);
        __builtin_amdgcn_s_setprio(0);
        __builtin_amdgcn_sched_barrier(0);
        asm volatile("s_waitcnt vmcnt(0)" ::: "memory");
        __builtin_amdgcn_s_barrier();
    }

    // top-2 per point within this nb: key = (sortkey(dist) & ~1023) | n
    float wq[4];
    #pragma unroll
    for (int fj = 0; fj < 4; ++fj) wq[fj] = wsq[nb * 128 + cn + fj * 16 + rl];

    #pragma unroll
    for (int fi = 0; fi < 4; ++fi) {
        #pragma unroll
        for (int r = 0; r < 4; ++r) {
            u32 b = 0xFFFFFFFFu, s = 0xFFFFFFFFu;
            #pragma unroll
            for (int fj = 0; fj < 4; ++fj) {
                float dist = wq[fj] - 2.0f * acc[fi][fj][r];
                u32 n = (u32)(nb * 128 + cn + fj * 16 + rl);
                u32 cand = (sortkey(dist) & 0xFFFFFC00u) | n;
                if (cand < b) { s = b; b = cand; }
                else if (cand < s) { s = cand; }
            }
            #pragma unroll
            for (int m2 = 1; m2 <= 8; m2 <<= 1) {
                u32 qb = (u32)__shfl_xor((int)b, m2, 64);
                u32 qs = (u32)__shfl_xor((int)s, m2, 64);
                u32 hi = b > qb ? b : qb;
                b = b < qb ? b : qb;
                s = s < qs ? s : qs;
                s = s < hi ? s : hi;
            }
            if (rl == 0) {
                int mloc = rm + fi * 16 + cg * 4 + r;
                red2[mloc][wn][0] = b;
                red2[mloc][wn][1] = s;
            }
        }
    }
    __syncthreads();
    if (tid < 128) {
        u32 b0 = red2[tid][0][0], s0 = red2[tid][0][1];
        u32 b1 = red2[tid][1][0], s1 = red2[tid][1][1];
        u32 B = b0 < b1 ? b0 : b1;
        u32 hi = b0 > b1 ? b0 : b1;
        u32 S = s0 < s1 ? s0 : s1;
        S = S < hi ? S : hi;
        u32* dst = best2 + ((size_t)mb * 128 + tid) * 16 + nb * 2;
        dst[0] = B;
        dst[1] = S;
    }
}

// ---- refine candidates exactly in f32, gather codes, write output, loss, usage ----
extern "C" __global__ __launch_bounds__(256) void vq_refine(const float* __restrict__ inp,
                                                            const float* __restrict__ w,
                                                            const u32* __restrict__ best2,
                                                            float* __restrict__ outq,
                                                            float* __restrict__ usage,
                                                            float* __restrict__ partial) {
    __shared__ float sp[2][128][17];
    __shared__ int sidx[128];
    __shared__ float wred[4];
    int blk = blockIdx.x, t = threadIdx.x;
    int p0 = blk * 128;
    int b = blk >> 3, hw0 = (blk & 7) * 128;
    int pi = t & 127, dh = t >> 7;

    u32 c16[16];
    {
        const uint4* cp = (const uint4*)(best2 + (size_t)(p0 + pi) * 16);
        uint4 q0 = cp[0], q1 = cp[1], q2 = cp[2], q3 = cp[3];
        c16[0] = q0.x; c16[1] = q0.y; c16[2] = q0.z; c16[3] = q0.w;
        c16[4] = q1.x; c16[5] = q1.y; c16[6] = q1.z; c16[7] = q1.w;
        c16[8] = q2.x; c16[9] = q2.y; c16[10] = q2.z; c16[11] = q2.w;
        c16[12] = q3.x; c16[13] = q3.y; c16[14] = q3.z; c16[15] = q3.w;
    }
    u32 minc = c16[0];
    #pragma unroll
    for (int c = 1; c < 16; ++c) minc = c16[c] < minc ? c16[c] : minc;
    const float thr = inv_sortkey(minc & 0xFFFFFC00u) + 1.0f;

    const float* xcol = inp + (size_t)b * 262144 + hw0 + pi;
    #pragma unroll
    for (int c = 0; c < 16; ++c) {
        u32 key = c16[c];
        float cd = inv_sortkey(key & 0xFFFFFC00u);
        if (cd <= thr) {
            int k = (int)(key & 1023u);
            const float* wr = w + (size_t)k * 256 + dh * 128;
            float a2 = 0.0f;
            #pragma unroll 4
            for (int d = 0; d < 128; d += 4) {
                float4 wv = *(const float4*)(wr + d);
                float x0 = xcol[(size_t)(dh * 128 + d + 0) * 1024];
                float x1 = xcol[(size_t)(dh * 128 + d + 1) * 1024];
                float x2 = xcol[(size_t)(dh * 128 + d + 2) * 1024];
                float x3 = xcol[(size_t)(dh * 128 + d + 3) * 1024];
                float d0 = x0 - wv.x, d1 = x1 - wv.y, d2 = x2 - wv.z, d3 = x3 - wv.w;
                a2 = fmaf(d0, d0, a2); a2 = fmaf(d1, d1, a2);
                a2 = fmaf(d2, d2, a2); a2 = fmaf(d3, d3, a2);
            }
            sp[dh][pi][c] = a2;
        }
    }
    __syncthreads();
    float lsum = 0.0f;
    if (t < 128) {
        float bestd = 3.4e38f;
        int bestk = 1 << 20;
        #pragma unroll
        for (int c = 0; c < 16; ++c) {
            u32 key = c16[c];
            float cd = inv_sortkey(key & 0xFFFFFC00u);
            if (cd <= thr) {
                float d2 = sp[0][pi][c] + sp[1][pi][c];
                int k = (int)(key & 1023u);
                if (d2 < bestd || (d2 == bestd && k < bestk)) { bestd = d2; bestk = k; }
            }
        }
        sidx[pi] = bestk;
        atomicAdd(usage + bestk, 1.0f);  // integer-valued f32: exact, order-independent
        lsum = bestd;
    }
    __syncthreads();
    float* ob = outq + (size_t)b * 262144 + hw0 + pi;
    const float* wrow = w + (size_t)sidx[pi] * 256;
    #pragma unroll 4
    for (int d4 = 0; d4 < 32; ++d4) {
        int d = dh * 128 + d4 * 4;
        float4 q = *(const float4*)(wrow + d);
        ob[(size_t)d * 1024] = q.x;
        ob[(size_t)(d + 1) * 1024] = q.y;
        ob[(size_t)(d + 2) * 1024] = q.z;
        ob[(size_t)(d + 3) * 1024] = q.w;
    }
    #pragma unroll
    for (int off = 32; off >= 1; off >>= 1) lsum += __shfl_xor(lsum, off, 64);
    if ((t & 63) == 0) wred[t >> 6] = lsum;
    __syncthreads();
    if (t == 0) partial[blk] = (wred[0] + wred[1]) + (wred[2] + wred[3]);
}

extern "C" __global__ __launch_bounds__(256) void vq_final(const float* __restrict__ partial,
                                                           float* __restrict__ loss) {
    __shared__ float sm[256];
    int t = threadIdx.x;
    sm[t] = partial[t];
    __syncthreads();
    #pragma unroll
    for (int off = 128; off >= 1; off >>= 1) {
        if (t < off) sm[t] += sm[t + off];
        __syncthreads();
    }
    if (t == 0) loss[0] = sm[0] * (1.25f / 8388608.0f);
}

extern "C" void kernel_launch(void* const* d_in, const int* in_sizes, int n_in,
                              void* d_out, int out_size, void* d_ws, size_t ws_size,
                              hipStream_t stream) {
    const float* inp = (const float*)d_in[0];
    const float* w = (const float*)d_in[1];
    float* outq = (float*)d_out;
    float* loss = outq + NQ;
    float* usage = outq + NQ + 1;

    char* Aimg = (char*)d_out;  // 16 MiB staging, overwritten by vq_refine
    char* ws = (char*)d_ws;
    char* Wimg = ws;                                  // 512 KiB
    float* wsq = (float*)(ws + 524288);               // 4 KiB
    u32* best2 = (u32*)(ws + 524288 + 4096);          // 2 MiB
    float* partial = (float*)(ws + 524288 + 4096 + 2097152);  // 1 KiB

    vq_conv<<<384, 256, 0, stream>>>(inp, w, Aimg, Wimg, wsq, usage);
    vq_coarse<<<2048, 256, 0, stream>>>(Aimg, Wimg, wsq, best2);
    vq_refine<<<256, 256, 0, stream>>>(inp, w, best2, outq, usage, partial);
    vq_final<<<1, 256, 0, stream>>>(partial, loss);
}

// Round 5
// 85.862 us; speedup vs baseline: 1.4155x; 1.4155x over previous
//
#include <hip/hip_runtime.h>

// VQ-VAE forward, two-stage argmin:
//   1) coarse fp16 MFMA GEMM (K=256) + fused top-2-per-nb candidate extraction
//   2) exact f32 refinement (compacted candidates, x-in-regs) + gather + loss
// d_out: [0,8388608) quantized f32 | [8388608] loss | [8388609,+1024) usage
// d_out[0,16MiB) doubles as the f16 A-image (conv -> coarse), overwritten by refine.
// d_ws: [0,512K) W-f16 image | +4K wsq | +2M best2 (u32 key22|idx10) | +4K partial.

typedef _Float16 f16;
typedef __attribute__((ext_vector_type(8))) f16 f16x8;
typedef __attribute__((ext_vector_type(4))) float f32x4;
typedef unsigned int u32;

#define NQ 8388608

__device__ __forceinline__ u32 sortkey(float f) {
    u32 u = __float_as_uint(f);
    return (u & 0x80000000u) ? ~u : (u | 0x80000000u);
}
__device__ __forceinline__ float inv_sortkey(u32 u) {
    return (u & 0x80000000u) ? __uint_as_float(u & 0x7FFFFFFFu) : __uint_as_float(~u);
}

// ---- merged conversion kernel ----
// blocks 0..255: inputs -> A-f16 image [mb 0..255][t 0..7][cg 0..3][row 0..127][16B]
// blocks 256..383: weight -> W-f16 image [nb 0..7][t][cg][col][16B] + wsq + usage=0
extern "C" __global__ __launch_bounds__(256) void vq_conv(const float* __restrict__ inp,
                                                          const float* __restrict__ w,
                                                          char* __restrict__ Aimg,
                                                          char* __restrict__ Wimg,
                                                          float* __restrict__ wsq,
                                                          float* __restrict__ usage) {
    int blk = blockIdx.x, tid = threadIdx.x;
    if (blk < 256) {
        __shared__ float xt[64 * 128];
        int mb = blk;
        int b = mb >> 3, hw0 = (mb & 7) * 128;
        const float* base = inp + (size_t)b * 262144 + hw0;
        char* Ab = Aimg + (size_t)mb * 65536;
        for (int dcb = 0; dcb < 4; ++dcb) {
            __syncthreads();
            #pragma unroll
            for (int it = 0; it < 8; ++it) {
                int e = it * 256 + tid;
                int dd = e >> 5, h4 = e & 31;
                float4 v = *(const float4*)(base + (size_t)(dcb * 64 + dd) * 1024 + h4 * 4);
                *(float4*)(xt + dd * 128 + h4 * 4) = v;
            }
            __syncthreads();
            #pragma unroll
            for (int it2 = 0; it2 < 4; ++it2) {
                int task = it2 * 256 + tid;
                int g = task >> 7, row = task & 127;
                union { f16 h[8]; uint4 v; } pk;
                #pragma unroll
                for (int j = 0; j < 8; ++j) pk.h[j] = (f16)xt[(g * 8 + j) * 128 + row];
                int t_img = dcb * 2 + (g >> 2), cg = g & 3;
                *(uint4*)(Ab + (size_t)t_img * 8192 + cg * 2048 + row * 16) = pk.v;
            }
        }
    } else {
        int gid = (blk - 256) * 256 + tid;  // 32768 = 1024 n x 32 dc
        int n = gid >> 5, dc = gid & 31;
        const float* src = w + n * 256 + dc * 8;
        float4 v0 = *(const float4*)src;
        float4 v1 = *(const float4*)(src + 4);
        float xs[8] = {v0.x, v0.y, v0.z, v0.w, v1.x, v1.y, v1.z, v1.w};
        union { f16 h[8]; uint4 v; } pk;
        float sq = 0.0f;
        #pragma unroll
        for (int j = 0; j < 8; ++j) {
            pk.h[j] = (f16)xs[j];
            sq += xs[j] * xs[j];
        }
        int nb = n >> 7, col = n & 127;
        *(uint4*)(Wimg + (size_t)nb * 65536 + (dc >> 2) * 8192 + (dc & 3) * 2048 + col * 16) = pk.v;
        #pragma unroll
        for (int m = 1; m <= 16; m <<= 1) sq += __shfl_xor(sq, m, 64);
        if ((tid & 31) == 0) { wsq[n] = sq; usage[n] = 0.0f; }
    }
}

// ---- coarse fp16 GEMM 128x128xK256 + fused top-2-per-nb argmin ----
extern "C" __global__ __launch_bounds__(256) void vq_coarse(const char* __restrict__ Aimg,
                                                            const char* __restrict__ Wimg,
                                                            const float* __restrict__ wsq,
                                                            u32* __restrict__ best2) {
    __shared__ __align__(16) char smem[32768];  // 2 bufs x (A 8K + B 8K)
    __shared__ u32 red2[128][2][2];
    const int tid = threadIdx.x, lane = tid & 63, wv = tid >> 6;
    const int wm = wv >> 1, wn = wv & 1;
    const int rm = wm * 64, cn = wn * 64;
    const int cg = lane >> 4, rl = lane & 15;
    int bid = blockIdx.x;
    int lb = (bid & 7) * 256 + (bid >> 3);  // XCD-chunked swizzle (2048 % 8 == 0)
    const int mb = lb >> 3, nb = lb & 7;

    const char* Ag = Aimg + (size_t)mb * 65536;
    const char* Bg = Wimg + (size_t)nb * 65536;

    f32x4 acc[4][4];
    #pragma unroll
    for (int i = 0; i < 4; ++i)
        #pragma unroll
        for (int j = 0; j < 4; ++j) acc[i][j] = (f32x4){0.f, 0.f, 0.f, 0.f};

    auto stage = [&](int T) {
        const char* ga = Ag + (size_t)T * 8192;
        const char* gb = Bg + (size_t)T * 8192;
        char* la = smem + (T & 1) * 16384;
        char* lb2 = la + 8192;
        __builtin_amdgcn_global_load_lds(
            (const __attribute__((address_space(1))) u32*)(ga + tid * 16),
            (__attribute__((address_space(3))) u32*)(la + tid * 16), 16, 0, 0);
        __builtin_amdgcn_global_load_lds(
            (const __attribute__((address_space(1))) u32*)(ga + tid * 16 + 4096),
            (__attribute__((address_space(3))) u32*)(la + tid * 16 + 4096), 16, 0, 0);
        __builtin_amdgcn_global_load_lds(
            (const __attribute__((address_space(1))) u32*)(gb + tid * 16),
            (__attribute__((address_space(3))) u32*)(lb2 + tid * 16), 16, 0, 0);
        __builtin_amdgcn_global_load_lds(
            (const __attribute__((address_space(1))) u32*)(gb + tid * 16 + 4096),
            (__attribute__((address_space(3))) u32*)(lb2 + tid * 16 + 4096), 16, 0, 0);
    };

    stage(0);
    asm volatile("s_waitcnt vmcnt(0)" ::: "memory");
    __builtin_amdgcn_s_barrier();

    for (int T = 0; T < 8; ++T) {
        if (T < 7) stage(T + 1);
        const char* Ab = smem + (T & 1) * 16384 + cg * 2048;
        const char* Bb = Ab + 8192;
        f16x8 af[4], bf[4];
        #pragma unroll
        for (int f = 0; f < 4; ++f) {
            af[f] = *(const f16x8*)(Ab + (rm + f * 16 + rl) * 16);
            bf[f] = *(const f16x8*)(Bb + (cn + f * 16 + rl) * 16);
        }
        __builtin_amdgcn_sched_barrier(0);
        asm volatile("s_waitcnt lgkmcnt(0)" ::: "memory");
        __builtin_amdgcn_sched_barrier(0);
        __builtin_amdgcn_s_setprio(1);
        #pragma unroll
        for (int fi = 0; fi < 4; ++fi)
            #pragma unroll
            for (int fj = 0; fj < 4; ++fj)
                acc[fi][fj] = __builtin_amdgcn_mfma_f32_16x16x32_f16(af[fi], bf[fj],
                                                                    acc[fi][fj], 0, 0, 0);
        __builtin_amdgcn_s_setprio(0);
        __builtin_amdgcn_sched_barrier(0);
        asm volatile("s_waitcnt vmcnt(0)" ::: "memory");
        __builtin_amdgcn_s_barrier();
    }

    // top-2 per point within this nb: key = (sortkey(dist) & ~1023) | n
    float wq[4];
    #pragma unroll
    for (int fj = 0; fj < 4; ++fj) wq[fj] = wsq[nb * 128 + cn + fj * 16 + rl];

    #pragma unroll
    for (int fi = 0; fi < 4; ++fi) {
        #pragma unroll
        for (int r = 0; r < 4; ++r) {
            u32 b = 0xFFFFFFFFu, s = 0xFFFFFFFFu;
            #pragma unroll
            for (int fj = 0; fj < 4; ++fj) {
                float dist = wq[fj] - 2.0f * acc[fi][fj][r];
                u32 n = (u32)(nb * 128 + cn + fj * 16 + rl);
                u32 cand = (sortkey(dist) & 0xFFFFFC00u) | n;
                if (cand < b) { s = b; b = cand; }
                else if (cand < s) { s = cand; }
            }
            #pragma unroll
            for (int m2 = 1; m2 <= 8; m2 <<= 1) {
                u32 qb = (u32)__shfl_xor((int)b, m2, 64);
                u32 qs = (u32)__shfl_xor((int)s, m2, 64);
                u32 hi = b > qb ? b : qb;
                b = b < qb ? b : qb;
                s = s < qs ? s : qs;
                s = s < hi ? s : hi;
            }
            if (rl == 0) {
                int mloc = rm + fi * 16 + cg * 4 + r;
                red2[mloc][wn][0] = b;
                red2[mloc][wn][1] = s;
            }
        }
    }
    __syncthreads();
    if (tid < 128) {
        u32 b0 = red2[tid][0][0], s0 = red2[tid][0][1];
        u32 b1 = red2[tid][1][0], s1 = red2[tid][1][1];
        u32 B = b0 < b1 ? b0 : b1;
        u32 hi = b0 > b1 ? b0 : b1;
        u32 S = s0 < s1 ? s0 : s1;
        S = S < hi ? S : hi;
        u32* dst = best2 + ((size_t)mb * 128 + tid) * 16 + nb * 2;
        dst[0] = B;
        dst[1] = S;
    }
}

// ---- exact f32 refine: 32 points/block, compacted candidates, x in registers ----
extern "C" __global__ __launch_bounds__(256) void vq_refine(const float* __restrict__ inp,
                                                            const float* __restrict__ w,
                                                            const u32* __restrict__ best2,
                                                            float* __restrict__ outq,
                                                            float* __restrict__ usage,
                                                            float* __restrict__ partial) {
    __shared__ float sp[8][33];
    __shared__ int km[32][17];
    __shared__ int sidx[32];
    __shared__ int sM;
    int blk = blockIdx.x, t = threadIdx.x;
    int pi = t & 31, dg = t >> 5;  // 8 d-groups of 32
    int p = blk * 32 + pi;
    int b = p >> 10, hw = p & 1023;
    const float* xcol = inp + (size_t)b * 262144 + hw;

    if (t == 0) sM = 0;

    // x into registers (32 d's per thread; coalesced 128B per 32 lanes)
    float xr[32];
    #pragma unroll
    for (int j = 0; j < 32; ++j) xr[j] = xcol[(size_t)(dg * 32 + j) * 1024];

    // candidates (same 64B row read by all 8 dg threads of a point; L2-resident)
    u32 ca[16];
    {
        const uint4* cp = (const uint4*)(best2 + (size_t)p * 16);
        uint4 q0 = cp[0], q1 = cp[1], q2 = cp[2], q3 = cp[3];
        ca[0] = q0.x; ca[1] = q0.y; ca[2] = q0.z; ca[3] = q0.w;
        ca[4] = q1.x; ca[5] = q1.y; ca[6] = q1.z; ca[7] = q1.w;
        ca[8] = q2.x; ca[9] = q2.y; ca[10] = q2.z; ca[11] = q2.w;
        ca[12] = q3.x; ca[13] = q3.y; ca[14] = q3.z; ca[15] = q3.w;
    }
    u32 minc = ca[0];
    #pragma unroll
    for (int c = 1; c < 16; ++c) minc = ca[c] < minc ? ca[c] : minc;
    const float thr = inv_sortkey(minc & 0xFFFFFC00u) + 1.0f;

    // compact passing candidates (all dg threads compute m; dg==0 writes list)
    int m = 0;
    #pragma unroll
    for (int c = 0; c < 16; ++c) {
        u32 key = ca[c];
        if (inv_sortkey(key & 0xFFFFFC00u) <= thr) {
            if (dg == 0) km[pi][m] = (int)(key & 1023u);
            ++m;
        }
    }
    __syncthreads();
    if (t < 32) atomicMax(&sM, m);
    __syncthreads();
    const int M = sM;

    float bestd = 3.4e38f;
    int bestk = 1 << 20;
    for (int i = 0; i < M; ++i) {
        int k = (i < m) ? km[pi][i] : 0;
        const float* wr = w + (size_t)k * 256 + dg * 32;
        float a2 = 0.0f;
        #pragma unroll
        for (int j4 = 0; j4 < 8; ++j4) {
            float4 wv = *(const float4*)(wr + j4 * 4);
            float d0 = xr[j4 * 4 + 0] - wv.x;
            float d1 = xr[j4 * 4 + 1] - wv.y;
            float d2 = xr[j4 * 4 + 2] - wv.z;
            float d3 = xr[j4 * 4 + 3] - wv.w;
            a2 = fmaf(d0, d0, a2); a2 = fmaf(d1, d1, a2);
            a2 = fmaf(d2, d2, a2); a2 = fmaf(d3, d3, a2);
        }
        sp[dg][pi] = a2;
        __syncthreads();
        if (t < 32 && i < m) {
            float d2s = ((sp[0][pi] + sp[1][pi]) + (sp[2][pi] + sp[3][pi])) +
                        ((sp[4][pi] + sp[5][pi]) + (sp[6][pi] + sp[7][pi]));
            int k0 = km[pi][i];
            if (d2s < bestd || (d2s == bestd && k0 < bestk)) { bestd = d2s; bestk = k0; }
        }
        __syncthreads();
    }

    float lsum = 0.0f;
    if (t < 32) {
        sidx[pi] = bestk;
        atomicAdd(usage + bestk, 1.0f);  // integer-valued f32: exact, order-independent
        lsum = bestd;                    // exact ||x - w_best||^2
    }
    __syncthreads();

    // gather + coalesced strided write
    const float* wr = w + (size_t)sidx[pi] * 256 + dg * 32;
    float* ob = outq + (size_t)b * 262144 + hw;
    #pragma unroll
    for (int j4 = 0; j4 < 8; ++j4) {
        float4 wv = *(const float4*)(wr + j4 * 4);
        ob[(size_t)(dg * 32 + j4 * 4 + 0) * 1024] = wv.x;
        ob[(size_t)(dg * 32 + j4 * 4 + 1) * 1024] = wv.y;
        ob[(size_t)(dg * 32 + j4 * 4 + 2) * 1024] = wv.z;
        ob[(size_t)(dg * 32 + j4 * 4 + 3) * 1024] = wv.w;
    }

    // loss partial: lanes 0..31 of wave 0 hold lsum; offsets <=16 stay in-half
    #pragma unroll
    for (int off = 16; off >= 1; off >>= 1) lsum += __shfl_xor(lsum, off, 64);
    if (t == 0) partial[blk] = lsum;
}

extern "C" __global__ __launch_bounds__(256) void vq_final(const float* __restrict__ partial,
                                                           float* __restrict__ loss) {
    __shared__ float sm[256];
    int t = threadIdx.x;
    sm[t] = (partial[t] + partial[t + 256]) + (partial[t + 512] + partial[t + 768]);
    __syncthreads();
    #pragma unroll
    for (int off = 128; off >= 1; off >>= 1) {
        if (t < off) sm[t] += sm[t + off];
        __syncthreads();
    }
    if (t == 0) loss[0] = sm[0] * (1.25f / 8388608.0f);
}

extern "C" void kernel_launch(void* const* d_in, const int* in_sizes, int n_in,
                              void* d_out, int out_size, void* d_ws, size_t ws_size,
                              hipStream_t stream) {
    const float* inp = (const float*)d_in[0];
    const float* w = (const float*)d_in[1];
    float* outq = (float*)d_out;
    float* loss = outq + NQ;
    float* usage = outq + NQ + 1;

    char* Aimg = (char*)d_out;  // 16 MiB staging, overwritten by vq_refine
    char* ws = (char*)d_ws;
    char* Wimg = ws;                                          // 512 KiB
    float* wsq = (float*)(ws + 524288);                       // 4 KiB
    u32* best2 = (u32*)(ws + 524288 + 4096);                  // 2 MiB
    float* partial = (float*)(ws + 524288 + 4096 + 2097152);  // 4 KiB

    vq_conv<<<384, 256, 0, stream>>>(inp, w, Aimg, Wimg, wsq, usage);
    vq_coarse<<<2048, 256, 0, stream>>>(Aimg, Wimg, wsq, best2);
    vq_refine<<<1024, 256, 0, stream>>>(inp, w, best2, outq, usage, partial);
    vq_final<<<1, 256, 0, stream>>>(partial, loss);
}